// Round 1
// 580.197 us; speedup vs baseline: 1.0131x; 1.0131x over previous
//
#include <hip/hip_runtime.h>
#include <hip/hip_bf16.h>

typedef __hip_bfloat16 bf16;
typedef __attribute__((ext_vector_type(8))) __bf16 bf16x8;
typedef __attribute__((ext_vector_type(4))) float f32x4;

#define B_ 16384
#define D_ 1024
#define H_ 512
#define O_ 256
#define E_ 8
#define BC_ 8192   // B-chunk rows for expert L1/L2/L3 (ws budget)

static_assert(B_ % BC_ == 0, "chunking");

// async global->LDS, 16B per lane (m97/m201 staging path).
#define GLDS(src, dst) __builtin_amdgcn_global_load_lds( \
    (const __attribute__((address_space(1))) void*)(src), \
    (__attribute__((address_space(3))) void*)(dst), 16, 0, 0)

#define BAR()   asm volatile("s_barrier" ::: "memory")
#define LGKM0() do { asm volatile("s_waitcnt lgkmcnt(0)" ::: "memory"); \
                     __builtin_amdgcn_sched_barrier(0); } while (0)

// ---------------------------------------------------------------------------
// Input-dtype detector. flag=1 => inputs are fp32.
// ---------------------------------------------------------------------------
__global__ void detect_k(const unsigned short* __restrict__ x, int* __restrict__ flag) {
    __shared__ int s;
    if (threadIdx.x == 0) s = 0;
    __syncthreads();
    int big = 0;
    for (int i = threadIdx.x; i < 2048; i += 256)
        if (((x[i] >> 7) & 0xFF) >= 150) big = 1;
    if (big) atomicOr(&s, 1);
    __syncthreads();
    if (threadIdx.x == 0) *flag = s;
}

// canonicalize any input to bf16 (grid-stride)
__global__ void cvt_k(const void* __restrict__ src, bf16* __restrict__ dst,
                      const int* __restrict__ flag, long n) {
    const int f = *flag;
    long i = (long)blockIdx.x * blockDim.x + threadIdx.x;
    const long stride = (long)gridDim.x * blockDim.x;
    if (f) {
        const float* s = (const float*)src;
        for (; i < n; i += stride) dst[i] = __float2bfloat16(s[i]);
    } else {
        const bf16* s = (const bf16*)src;
        for (; i < n; i += stride) dst[i] = s[i];
    }
}

// ---------------------------------------------------------------------------
// Batched 2D transpose + canonicalize: in [Z][R][C] ->
//   out[z*z_out + c*c_stride + r]  (z_out=R*C,c_stride=R gives [Z][C][R])
// ---------------------------------------------------------------------------
__global__ void transpose_k(const void* __restrict__ in, bf16* __restrict__ out,
                            const int* __restrict__ flag, int R, int C,
                            long z_out, long c_stride) {
    __shared__ bf16 t[32][33];
    const int f = *flag;
    const long zi = (long)blockIdx.z * R * C;
    const int x = blockIdx.x * 32 + threadIdx.x;
    const int y0 = blockIdx.y * 32;
    const float* inf = (const float*)in;
    const bf16* inb = (const bf16*)in;
#pragma unroll
    for (int i = 0; i < 4; i++) {
        int r = y0 + threadIdx.y + i * 8;
        long idx = zi + (long)r * C + x;
        t[threadIdx.y + i * 8][threadIdx.x] =
            f ? __float2bfloat16(inf[idx]) : inb[idx];
    }
    __syncthreads();
    const int xr = blockIdx.y * 32 + threadIdx.x;
    const long zo = (long)blockIdx.z * z_out;
#pragma unroll
    for (int i = 0; i < 4; i++) {
        int c = blockIdx.x * 32 + threadIdx.y + i * 8;
        out[zo + (long)c * c_stride + xr] = t[threadIdx.x][threadIdx.y + i * 8];
    }
}

// ---------------------------------------------------------------------------
// Gating layer 3 + softmax: g2 [B,128] @ gw3 [128,8] + gb3 -> softmax -> gates
// ---------------------------------------------------------------------------
__global__ void gate3_softmax_k(const bf16* __restrict__ g2,
                                const bf16* __restrict__ gw3,
                                const bf16* __restrict__ gb3,
                                float* __restrict__ gates) {
    __shared__ float w[128 * 8];
    __shared__ float bsh[8];
    const int tid = threadIdx.x;
    for (int i = tid; i < 1024; i += 256) w[i] = __bfloat162float(gw3[i]);
    if (tid < 8) bsh[tid] = __bfloat162float(gb3[tid]);
    __syncthreads();

    const long row = (long)blockIdx.x * 256 + tid;
    float acc[8];
#pragma unroll
    for (int o = 0; o < 8; o++) acc[o] = bsh[o];

    const bf16x8* rp8 = (const bf16x8*)(g2 + row * 128);
#pragma unroll 4
    for (int c8 = 0; c8 < 16; c8++) {
        bf16x8 v8 = rp8[c8];
#pragma unroll
        for (int jj = 0; jj < 8; jj++) {
            float v = (float)v8[jj];
            int k = c8 * 8 + jj;
#pragma unroll
            for (int o = 0; o < 8; o++) acc[o] += v * w[k * 8 + o];
        }
    }
    float m = acc[0];
#pragma unroll
    for (int o = 1; o < 8; o++) m = fmaxf(m, acc[o]);
    float s = 0.f;
#pragma unroll
    for (int o = 0; o < 8; o++) { acc[o] = __expf(acc[o] - m); s += acc[o]; }
    const float inv = 1.f / s;
#pragma unroll
    for (int o = 0; o < 8; o++) gates[row * 8 + o] = acc[o] * inv;
}

// ---------------------------------------------------------------------------
// Legacy 128x128 GEMM (m97 structure). Used for small gating GEMMs + pathB.
// C[M,N] = A[M,K] * Bt[N,K]^T, BK=32, 4 waves.
// MODE 0: out = bf16(relu(acc + bias[c]))
// MODE 1: out = bf16(relu(acc + bias[c]) * gates[row0+r, e])
// MODE 2: outf32[r,c] += acc + gates[row0+r,e]*eb3[e,c]
// ---------------------------------------------------------------------------
template <int MODE>
__global__ __launch_bounds__(256, 4)
void gemm_bt(const bf16* __restrict__ A, const bf16* __restrict__ Bt,
             const bf16* __restrict__ bias, const float* __restrict__ gates,
             void* __restrict__ Cout, const bf16* __restrict__ eb3,
             const int* __restrict__ oflag,
             int lda, int ldb, int ldo, int K,
             long a_z, long b_z, long bias_z, long out_z,
             int e_gate, int k_per_e, long a_e, long b_e, long row0) {
    __shared__ __attribute__((aligned(16))) bf16 As[128 * 32];
    __shared__ __attribute__((aligned(16))) bf16 Bs[128 * 32];

    const int tid  = threadIdx.x;
    const int lane = tid & 63;
    const int quad = lane >> 4;
    const int l15  = lane & 15;
    const int wid  = tid >> 6;
    const int wr   = (wid >> 1) << 6;
    const int wc   = (wid & 1) << 6;
    const int z    = blockIdx.z;
    const long m0  = (long)blockIdx.y << 7;
    const long n0  = (long)blockIdx.x << 7;

    const bf16* Az = A + (long)z * a_z;
    const bf16* Bz = Bt + (long)z * b_z;

    f32x4 acc[4][4];
#pragma unroll
    for (int i = 0; i < 4; i++)
#pragma unroll
        for (int j = 0; j < 4; j++) acc[i][j] = (f32x4){0.f, 0.f, 0.f, 0.f};

    const int erow = tid >> 2;
    const int ecol = (tid & 3) << 3;

    const int n_e   = k_per_e ? (K / k_per_e) : 1;
    const int inner = (k_per_e ? k_per_e : K) >> 5;

    for (int e = 0; e < n_e; e++) {
        const bf16* Ae = Az + (long)e * a_e;
        const bf16* Be = Bz + (long)e * b_e;
        for (int kti = 0; kti < inner; kti++) {
            const int kk = kti << 5;
#pragma unroll
            for (int i = 0; i < 2; i++) {
                const int r = (i << 6) + erow;
                GLDS(Ae + (m0 + r) * lda + (kk + ecol), As + r * 32 + ecol);
            }
#pragma unroll
            for (int i = 0; i < 2; i++) {
                const int r = (i << 6) + erow;
                GLDS(Be + (n0 + r) * ldb + (kk + ecol), Bs + r * 32 + ecol);
            }
            __syncthreads();
            bf16x8 af[4], bfr[4];
#pragma unroll
            for (int i = 0; i < 4; i++)
                af[i] = *(const bf16x8*)(As + (wr + i * 16 + l15) * 32 + (quad << 3));
#pragma unroll
            for (int j = 0; j < 4; j++)
                bfr[j] = *(const bf16x8*)(Bs + (wc + j * 16 + l15) * 32 + (quad << 3));
#pragma unroll
            for (int i = 0; i < 4; i++)
#pragma unroll
                for (int j = 0; j < 4; j++)
                    acc[i][j] = __builtin_amdgcn_mfma_f32_16x16x32_bf16(
                        af[i], bfr[j], acc[i][j], 0, 0, 0);
            __syncthreads();
        }
    }

    const int eg = (e_gate >= 0) ? e_gate : z;

    if constexpr (MODE == 0 || MODE == 1) {
        bf16* C = (bf16*)Cout + (long)z * out_z;
        const bf16* bb = bias + (long)z * bias_z;
        float gv[4][4];
        if constexpr (MODE == 1) {
#pragma unroll
            for (int i = 0; i < 4; i++)
#pragma unroll
                for (int rg = 0; rg < 4; rg++)
                    gv[i][rg] = gates[(row0 + m0 + wr + i * 16 + quad * 4 + rg) * 8 + eg];
        }
#pragma unroll
        for (int j = 0; j < 4; j++) {
            const int c = (int)n0 + wc + j * 16 + l15;
            const float bv = __bfloat162float(bb[c]);
#pragma unroll
            for (int i = 0; i < 4; i++) {
#pragma unroll
                for (int rg = 0; rg < 4; rg++) {
                    const long r = m0 + wr + i * 16 + quad * 4 + rg;
                    float v = fmaxf(acc[i][j][rg] + bv, 0.f);
                    if constexpr (MODE == 1) v *= gv[i][rg];
                    C[r * ldo + c] = __float2bfloat16(v);
                }
            }
        }
    } else if constexpr (MODE == 2) {
        float* C = (float*)Cout;
#pragma unroll
        for (int i = 0; i < 4; i++) {
#pragma unroll
            for (int rg = 0; rg < 4; rg++) {
                const long r = m0 + wr + i * 16 + quad * 4 + rg;
                const float g = gates[(row0 + r) * 8 + eg];
#pragma unroll
                for (int j = 0; j < 4; j++) {
                    const int c = (int)n0 + wc + j * 16 + l15;
                    const float b3 = __bfloat162float(eb3[eg * O_ + c]);
                    C[r * ldo + c] += acc[i][j][rg] + g * b3;
                }
            }
        }
    }
}

// ---------------------------------------------------------------------------
// 256x256-tile 8-phase GEMM (m201 structure: T1+T2+T3+T4+T5).
// C[M,N] = A[M,K] * Bt[N,K]^T. BK=64, 512 threads = 8 waves (2M x 4N),
// LDS 128 KiB double-buffered, st_16x32 XOR swizzle (col^16 when row&4),
// one half-tile staged per phase via global_load_lds w=16 (pre-swizzled src),
// counted vmcnt(4) at phases 4/8 only (vmcnt(0) drain on last iteration),
// s_setprio(1) around each 16-MFMA quadrant cluster.
//
// Per-iteration schedule (tiles t0=2i in buf0 / t1=2i+1 in buf1):
//  P0 rd(A0,B0|buf0) st Ah1(t1)   P4 rd(A0,B0|buf1) st Ah1(t2)
//  P1 rd(B1|buf0)    st Bh1(t1)   P5 rd(B1|buf1)    st Bh1(t2)
//  P2 rd(A1,B0|buf0) st Ah0(t2)   P6 rd(A1,B0|buf1) st Ah0(t3)
//  P3 rd(B1|buf0)    st Bh0(t2)   P7 rd(B1|buf1)    st Bh0(t3)
//  vmcnt(4) after P3/P7.  (Race-freedom: every staged region's last ds_read
//  is >=1 barrier earlier; every read is covered by a prior vmcnt+barrier.)
//
// MODE 0: bf16 out = relu(acc + bias[c])                    (z-batched)
// MODE 1: bf16 out = relu(acc + bias[c]) * gates[row0+r,z]  (z-batched)
// MODE 4: fp32 parts[z][r][c] = acc + gates[row0+r,z]*eb3[z,c]  (split-K)
// ---------------------------------------------------------------------------
template <int MODE>
__global__ __launch_bounds__(512, 2)
void gemm256(const bf16* __restrict__ A, const bf16* __restrict__ Bt,
             const bf16* __restrict__ bias, const float* __restrict__ gates,
             void* __restrict__ Cout, const bf16* __restrict__ eb3,
             int lda, int ldb, int ldo, int K,
             long a_z, long b_z, long bias_z, long out_z, long row0) {
    __shared__ __attribute__((aligned(16))) bf16 lds[2][2][256 * 64];

    // T1: bijective XCD swizzle (all launches have nwg%8==0 per z-slice)
    int bx = blockIdx.x, by = blockIdx.y;
    {
        const int gx = gridDim.x;
        const int nwg = gx * gridDim.y;
        if ((nwg & 7) == 0) {
            int lin = bx + gx * by;
            lin = (lin & 7) * (nwg >> 3) + (lin >> 3);
            bx = lin % gx; by = lin / gx;
        }
    }

    const int tid  = threadIdx.x;
    const int lane = tid & 63;
    const int quad = lane >> 4;
    const int l15  = lane & 15;
    const int w    = tid >> 6;
    const int wm   = w >> 2;
    const int wn   = w & 3;
    const int z    = blockIdx.z;
    const long m0  = (long)by << 8;
    const long n0  = (long)bx << 8;

    const bf16* __restrict__ Az = A + z * a_z;
    const bf16* __restrict__ Bz = Bt + z * b_z;

    f32x4 acc[8][4];
#pragma unroll
    for (int i = 0; i < 8; ++i)
#pragma unroll
        for (int j = 0; j < 4; ++j) acc[i][j] = (f32x4){0.f, 0.f, 0.f, 0.f};

    bf16x8 af[4][2], bv[2][2];

    // stage one half-tile (128 rows x 64 cols, 16 KB): 2 GLDS / thread.
    // LDS dest is linear (wave-uniform base + lane*16); swizzle applied by
    // permuting the per-lane GLOBAL source column (rule 21: both-sides).
    auto stage = [&](int buf, int mat, int half, int kt) {
        const bf16* __restrict__ G = mat ? Bz : Az;
        const int ld = mat ? ldb : lda;
        const long p0 = mat ? n0 : m0;
#pragma unroll
        for (int l = 0; l < 2; ++l) {
            const int ci = (w << 1) | l;                       // 0..15, wave-uniform
            const int rb = mat ? ((ci >> 2) << 6) + (half << 5) + ((ci & 3) << 3)
                               : ((ci >> 3) << 7) + (half << 6) + ((ci & 7) << 3);
            const int row = rb + (lane >> 3);
            const int cb  = ((lane & 7) << 4) ^ ((row & 4) << 3);  // T2 inverse-swz src
            GLDS(G + (p0 + row) * ld + kt * 64 + (cb >> 1),
                 &lds[buf][mat][rb * 64]);
        }
    };
    auto ldaf = [&](int buf, int qm) {   // A frags: rows wm*128+qm*64+i*16+l15
#pragma unroll
        for (int i = 0; i < 4; ++i) {
            const int r = (wm << 7) + (qm << 6) + (i << 4) + l15;
            const char* p = (const char*)&lds[buf][0][r * 64];
            const int sw = (r & 4) << 3;
#pragma unroll
            for (int s = 0; s < 2; ++s)
                af[i][s] = *(const bf16x8*)(p + (((s << 6) + (quad << 4)) ^ sw));
        }
    };
    auto ldbf = [&](int buf, int qn) {   // B frags: rows wn*64+qn*32+j*16+l15
#pragma unroll
        for (int j = 0; j < 2; ++j) {
            const int r = (wn << 6) + (qn << 5) + (j << 4) + l15;
            const char* p = (const char*)&lds[buf][1][r * 64];
            const int sw = (r & 4) << 3;
#pragma unroll
            for (int s = 0; s < 2; ++s)
                bv[j][s] = *(const bf16x8*)(p + (((s << 6) + (quad << 4)) ^ sw));
        }
    };
    auto mmac = [&](int qm, int qn) {    // 16 MFMA: one C quadrant x K=64
#pragma unroll
        for (int i = 0; i < 4; ++i)
#pragma unroll
            for (int j = 0; j < 2; ++j)
#pragma unroll
                for (int s = 0; s < 2; ++s)
                    acc[(qm << 2) + i][(qn << 1) + j] =
                        __builtin_amdgcn_mfma_f32_16x16x32_bf16(
                            af[i][s], bv[j][s], acc[(qm << 2) + i][(qn << 1) + j],
                            0, 0, 0);
    };

    const int nt = K >> 6;           // K-tiles (even, >=2 at all call sites)

    // prologue: tile0 full -> buf0; tile1 Ah0,Bh0 -> buf1; guarantee tile0.
    stage(0, 0, 0, 0); stage(0, 0, 1, 0); stage(0, 1, 0, 0); stage(0, 1, 1, 0);
    stage(1, 0, 0, 1); stage(1, 1, 0, 1);
    asm volatile("s_waitcnt vmcnt(4)" ::: "memory");
    BAR();

    const int hi = nt >> 1;
    for (int it = 0; it < hi; ++it) {
        const int t1k = 2 * it + 1, t2k = 2 * it + 2, t3k = 2 * it + 3;
        const bool do2 = t2k < nt, do3 = t3k < nt;
        // P0
        ldaf(0, 0); ldbf(0, 0); stage(1, 0, 1, t1k);
        BAR(); LGKM0();
        __builtin_amdgcn_s_setprio(1); mmac(0, 0); __builtin_amdgcn_s_setprio(0);
        BAR();
        // P1
        ldbf(0, 1); stage(1, 1, 1, t1k);
        BAR(); LGKM0();
        __builtin_amdgcn_s_setprio(1); mmac(0, 1); __builtin_amdgcn_s_setprio(0);
        BAR();
        // P2
        ldaf(0, 1); ldbf(0, 0); if (do2) stage(0, 0, 0, t2k);
        BAR(); LGKM0();
        __builtin_amdgcn_s_setprio(1); mmac(1, 0); __builtin_amdgcn_s_setprio(0);
        BAR();
        // P3
        ldbf(0, 1); if (do2) stage(0, 1, 0, t2k);
        BAR(); LGKM0();
        __builtin_amdgcn_s_setprio(1); mmac(1, 1); __builtin_amdgcn_s_setprio(0);
        if (do2) { asm volatile("s_waitcnt vmcnt(4)" ::: "memory"); }
        else     { asm volatile("s_waitcnt vmcnt(0)" ::: "memory"); }
        BAR();
        // P4
        ldaf(1, 0); ldbf(1, 0); if (do2) stage(0, 0, 1, t2k);
        BAR(); LGKM0();
        __builtin_amdgcn_s_setprio(1); mmac(0, 0); __builtin_amdgcn_s_setprio(0);
        BAR();
        // P5
        ldbf(1, 1); if (do2) stage(0, 1, 1, t2k);
        BAR(); LGKM0();
        __builtin_amdgcn_s_setprio(1); mmac(0, 1); __builtin_amdgcn_s_setprio(0);
        BAR();
        // P6
        ldaf(1, 1); ldbf(1, 0); if (do3) stage(1, 0, 0, t3k);
        BAR(); LGKM0();
        __builtin_amdgcn_s_setprio(1); mmac(1, 0); __builtin_amdgcn_s_setprio(0);
        BAR();
        // P7
        ldbf(1, 1); if (do3) stage(1, 1, 0, t3k);
        BAR(); LGKM0();
        __builtin_amdgcn_s_setprio(1); mmac(1, 1); __builtin_amdgcn_s_setprio(0);
        if (do3) { asm volatile("s_waitcnt vmcnt(4)" ::: "memory"); }
        else     { asm volatile("s_waitcnt vmcnt(0)" ::: "memory"); }
        BAR();
    }

    // ---------------- epilogue (C/D: row=quad*4+reg, col=l15) --------------
    if constexpr (MODE == 0 || MODE == 1) {
        bf16* C = (bf16*)Cout + z * out_z;
        const bf16* bb = bias + z * bias_z;
        float bvv[4];
#pragma unroll
        for (int jg = 0; jg < 4; ++jg)
            bvv[jg] = __bfloat162float(bb[(int)n0 + (wn << 6) + (jg << 4) + l15]);
#pragma unroll
        for (int ig = 0; ig < 8; ++ig) {
#pragma unroll
            for (int rg = 0; rg < 4; ++rg) {
                const long r = m0 + (wm << 7) + (ig << 4) + (quad << 2) + rg;
                float g = 1.f;
                if constexpr (MODE == 1) g = gates[(row0 + r) * 8 + z];
#pragma unroll
                for (int jg = 0; jg < 4; ++jg) {
                    const int c = (int)n0 + (wn << 6) + (jg << 4) + l15;
                    float v = fmaxf(acc[ig][jg][rg] + bvv[jg], 0.f);
                    if constexpr (MODE == 1) v *= g;
                    C[r * ldo + c] = __float2bfloat16(v);
                }
            }
        }
    } else {  // MODE 4: split-K partials, plain stores
        float* C = (float*)Cout + z * out_z;
        float b3v[4];
#pragma unroll
        for (int jg = 0; jg < 4; ++jg)
            b3v[jg] = __bfloat162float(eb3[z * O_ + (int)n0 + (wn << 6) + (jg << 4) + l15]);
#pragma unroll
        for (int ig = 0; ig < 8; ++ig) {
#pragma unroll
            for (int rg = 0; rg < 4; ++rg) {
                const long r = m0 + (wm << 7) + (ig << 4) + (quad << 2) + rg;
                const float g = gates[(row0 + r) * 8 + z];
#pragma unroll
                for (int jg = 0; jg < 4; ++jg) {
                    const int c = (int)n0 + (wn << 6) + (jg << 4) + l15;
                    C[r * ldo + c] = acc[ig][jg][rg] + g * b3v[jg];
                }
            }
        }
    }
}

// ---------------------------------------------------------------------------
__global__ void zero_f32_k(float* __restrict__ p) {
    p[(long)blockIdx.x * 256 + threadIdx.x] = 0.f;
}
__global__ void out_cvt_k(const float* __restrict__ in, void* __restrict__ out,
                          const int* __restrict__ flag) {
    const long i = (long)blockIdx.x * 256 + threadIdx.x;
    if (*flag) ((float*)out)[i] = in[i];
    else       ((bf16*)out)[i] = __float2bfloat16(in[i]);
}
// sum 8 split-K partial buffers [8][BC][O] -> d_out rows [off..off+BC*O)
__global__ void reduce8_k(const float* __restrict__ p, void* __restrict__ out,
                          const int* __restrict__ flag, long off) {
    const long n = (long)BC_ * O_;
    const long i = ((long)blockIdx.x * 256 + threadIdx.x) * 4;
    float4 s = *(const float4*)(p + i);
#pragma unroll
    for (int zz = 1; zz < 8; ++zz) {
        float4 a = *(const float4*)(p + (long)zz * n + i);
        s.x += a.x; s.y += a.y; s.z += a.z; s.w += a.w;
    }
    if (*flag) {
        *(float4*)((float*)out + off + i) = s;
    } else {
        bf16* o = (bf16*)out + off + i;
        o[0] = __float2bfloat16(s.x); o[1] = __float2bfloat16(s.y);
        o[2] = __float2bfloat16(s.z); o[3] = __float2bfloat16(s.w);
    }
}

// ---------------------------------------------------------------------------
extern "C" void kernel_launch(void* const* d_in, const int* in_sizes, int n_in,
                              void* d_out, int out_size, void* d_ws, size_t ws_size,
                              hipStream_t stream) {
    (void)in_sizes; (void)n_in; (void)out_size;
    const void* x   = d_in[0];
    const void* gw1 = d_in[1];
    const void* gb1 = d_in[2];
    const void* gw2 = d_in[3];
    const void* gb2 = d_in[4];
    const void* gw3 = d_in[5];
    const void* gb3 = d_in[6];
    const void* ew1 = d_in[7];
    const void* eb1 = d_in[8];
    const void* ew2 = d_in[9];
    const void* eb2 = d_in[10];
    const void* ew3 = d_in[11];
    const void* eb3 = d_in[12];

    char* ws = (char*)d_ws;
    size_t off = 0;
    auto alloc = [&](size_t n) { char* p = ws + off; off += (n + 255) & ~(size_t)255; return p; };

    int*  flag  = (int*)alloc(256);
    bf16* xc    = (bf16*)alloc((size_t)B_ * D_ * 2);
    bf16* gw1t  = (bf16*)alloc((size_t)256 * 1024 * 2);
    bf16* gw2t  = (bf16*)alloc((size_t)128 * 256 * 2);
    bf16* ew1t  = (bf16*)alloc((size_t)E_ * H_ * D_ * 2);
    bf16* ew2t  = (bf16*)alloc((size_t)E_ * H_ * H_ * 2);
    bf16* ew3t  = (bf16*)alloc((size_t)E_ * O_ * H_ * 2);
    bf16* gb1c  = (bf16*)alloc(256 * 2);
    bf16* gb2c  = (bf16*)alloc(128 * 2);
    bf16* gw3c  = (bf16*)alloc(1024 * 2);
    bf16* gb3c  = (bf16*)alloc(8 * 2);
    bf16* eb1c  = (bf16*)alloc((size_t)E_ * H_ * 2);
    bf16* eb2c  = (bf16*)alloc((size_t)E_ * H_ * 2);
    bf16* eb3c  = (bf16*)alloc((size_t)E_ * O_ * 2);
    bf16* g1    = (bf16*)alloc((size_t)B_ * 256 * 2);
    bf16* g2b   = (bf16*)alloc((size_t)B_ * 128 * 2);
    float* gates = (float*)alloc((size_t)B_ * 8 * 4);

    const size_t small = off;
    // path A: h1c [E][BC][H] + h2 [BC][E*H] (bf16) + parts fp32 [8][BC][O]
    const size_t needA = small + ((size_t)E_ * BC_ * H_ * 2 + 256)
                               + ((size_t)BC_ * E_ * H_ * 2 + 256)
                               + (8ull * BC_ * O_ * 4 + 256) + 4096;
    const bool pathA = ws_size >= needA;

    // 1) detect input dtype (flag=1 -> fp32)
    detect_k<<<1, 256, 0, stream>>>((const unsigned short*)x, flag);

    // 2) canonicalize to bf16
    cvt_k<<<4096, 256, 0, stream>>>(x, xc, flag, (long)B_ * D_);
    cvt_k<<<1, 256, 0, stream>>>(gb1, gb1c, flag, 256);
    cvt_k<<<1, 256, 0, stream>>>(gb2, gb2c, flag, 128);
    cvt_k<<<4, 256, 0, stream>>>(gw3, gw3c, flag, 1024);
    cvt_k<<<1, 256, 0, stream>>>(gb3, gb3c, flag, 8);
    cvt_k<<<16, 256, 0, stream>>>(eb1, eb1c, flag, (long)E_ * H_);
    cvt_k<<<16, 256, 0, stream>>>(eb2, eb2c, flag, (long)E_ * H_);
    cvt_k<<<8, 256, 0, stream>>>(eb3, eb3c, flag, (long)E_ * O_);

    // 3) weight transposes (K-contiguous rows, canonical bf16)
    transpose_k<<<dim3(256 / 32, 1024 / 32, 1), dim3(32, 8), 0, stream>>>(
        gw1, gw1t, flag, 1024, 256, 0L, 1024L);
    transpose_k<<<dim3(128 / 32, 256 / 32, 1), dim3(32, 8), 0, stream>>>(
        gw2, gw2t, flag, 256, 128, 0L, 256L);
    transpose_k<<<dim3(H_ / 32, D_ / 32, E_), dim3(32, 8), 0, stream>>>(
        ew1, ew1t, flag, D_, H_, (long)H_ * D_, (long)D_);
    transpose_k<<<dim3(H_ / 32, H_ / 32, E_), dim3(32, 8), 0, stream>>>(
        ew2, ew2t, flag, H_, H_, (long)H_ * H_, (long)H_);
    if (pathA)  // ew3t as [O][E][H]: single K=4096 L3 GEMM over concat experts
        transpose_k<<<dim3(O_ / 32, H_ / 32, E_), dim3(32, 8), 0, stream>>>(
            ew3, ew3t, flag, H_, O_, (long)H_, (long)E_ * H_);
    else        // legacy [E][O][H]
        transpose_k<<<dim3(O_ / 32, H_ / 32, E_), dim3(32, 8), 0, stream>>>(
            ew3, ew3t, flag, H_, O_, (long)O_ * H_, (long)H_);

    // 4) gating network (small N -> keep 128-tile kernel, full grid)
    gemm_bt<0><<<dim3(2, 128, 1), 256, 0, stream>>>(
        xc, gw1t, gb1c, nullptr, g1, nullptr, nullptr,
        1024, 1024, 256, 1024, 0, 0, 0, 0, 0, 0, 0, 0, 0);
    gemm_bt<0><<<dim3(1, 128, 1), 256, 0, stream>>>(
        g1, gw2t, gb2c, nullptr, g2b, nullptr, nullptr,
        256, 256, 128, 256, 0, 0, 0, 0, 0, 0, 0, 0, 0);
    gate3_softmax_k<<<dim3(B_ / 256), 256, 0, stream>>>(g2b, gw3c, gb3c, gates);

    // 5) experts
    if (pathA) {
        bf16* h1c   = (bf16*)alloc((size_t)E_ * BC_ * H_ * 2);   // [E][BC][H]
        bf16* h2    = (bf16*)alloc((size_t)BC_ * E_ * H_ * 2);   // [BC][E*H]
        float* parts = (float*)alloc(8ull * BC_ * O_ * 4);       // [8][BC][O]
        for (int ch = 0; ch < B_ / BC_; ch++) {
            const long rb = (long)ch * BC_;
            // L1 (z=e batched): h1c[e][r][h] = relu(x_chunk @ ew1[e] + eb1[e])
            gemm256<0><<<dim3(2, BC_ / 256, 8), 512, 0, stream>>>(
                xc + rb * D_, ew1t, eb1c, nullptr, h1c, nullptr,
                D_, D_, H_, D_,
                0, (long)H_ * D_, (long)H_, (long)BC_ * H_, 0);
            // L2 (z=e batched, gates folded): h2[r][e*H+h]
            gemm256<1><<<dim3(2, BC_ / 256, 8), 512, 0, stream>>>(
                h1c, ew2t, eb2c, gates, h2, nullptr,
                H_, H_, E_ * H_, H_,
                (long)BC_ * H_, (long)H_ * H_, (long)H_, (long)H_, rb);
            // L3 split-K over experts (z=8, K=512 each): parts[z] = partial
            gemm256<4><<<dim3(1, BC_ / 256, 8), 512, 0, stream>>>(
                h2, ew3t, nullptr, gates, parts, eb3c,
                E_ * H_, E_ * H_, O_, 512,
                (long)H_, (long)H_, 0, (long)BC_ * O_, rb);
            reduce8_k<<<dim3(BC_ * O_ / 1024), 256, 0, stream>>>(
                parts, d_out, flag, rb * O_);
        }
    } else {
        bf16* h1s = (bf16*)alloc((size_t)B_ * H_ * 2);
        bf16* h2s = (bf16*)alloc((size_t)B_ * H_ * 2);
        float* oacc = (float*)alloc((size_t)B_ * O_ * 4);
        zero_f32_k<<<dim3(B_ * O_ / 256), 256, 0, stream>>>(oacc);
        for (int e = 0; e < E_; e++) {
            gemm_bt<0><<<dim3(4, 128, 1), 256, 0, stream>>>(
                xc, ew1t + (size_t)e * H_ * D_, eb1c + (size_t)e * H_, nullptr, h1s, nullptr, nullptr,
                1024, 1024, 512, 1024, 0, 0, 0, 0, 0, 0, 0, 0, 0);
            gemm_bt<1><<<dim3(4, 128, 1), 256, 0, stream>>>(
                h1s, ew2t + (size_t)e * H_ * H_, eb2c + (size_t)e * H_, gates, h2s, nullptr, nullptr,
                512, 512, 512, 512, 0, 0, 0, 0, e, 0, 0, 0, 0);
            gemm_bt<2><<<dim3(2, 128, 1), 256, 0, stream>>>(
                h2s, ew3t + (size_t)e * O_ * H_, nullptr, gates, oacc, eb3c, nullptr,
                512, 512, 256, 512, 0, 0, 0, 0, e, 0, 0, 0, 0);
        }
        out_cvt_k<<<dim3(B_ * O_ / 256), 256, 0, stream>>>(oacc, d_out, flag);
    }
}

// Round 2
// 547.724 us; speedup vs baseline: 1.0732x; 1.0593x over previous
//
#include <hip/hip_runtime.h>
#include <hip/hip_bf16.h>

typedef __hip_bfloat16 bf16;
typedef __attribute__((ext_vector_type(8))) __bf16 bf16x8;
typedef __attribute__((ext_vector_type(4))) float f32x4;

#define B_ 16384
#define D_ 1024
#define H_ 512
#define O_ 256
#define E_ 8
#define BC_ 8192   // B-chunk rows for expert L1/L2/L3 (ws budget)

static_assert(B_ % BC_ == 0, "chunking");

// async global->LDS, 16B per lane (m97/m201 staging path).
#define GLDS(src, dst) __builtin_amdgcn_global_load_lds( \
    (const __attribute__((address_space(1))) void*)(src), \
    (__attribute__((address_space(3))) void*)(dst), 16, 0, 0)

#define BAR()   asm volatile("s_barrier" ::: "memory")
#define LGKM0() do { asm volatile("s_waitcnt lgkmcnt(0)" ::: "memory"); \
                     __builtin_amdgcn_sched_barrier(0); } while (0)

// ---------------------------------------------------------------------------
// Input-dtype detector. flag=1 => inputs are fp32.
// ---------------------------------------------------------------------------
__global__ void detect_k(const unsigned short* __restrict__ x, int* __restrict__ flag) {
    __shared__ int s;
    if (threadIdx.x == 0) s = 0;
    __syncthreads();
    int big = 0;
    for (int i = threadIdx.x; i < 2048; i += 256)
        if (((x[i] >> 7) & 0xFF) >= 150) big = 1;
    if (big) atomicOr(&s, 1);
    __syncthreads();
    if (threadIdx.x == 0) *flag = s;
}

// canonicalize any input to bf16 (grid-stride)
__global__ void cvt_k(const void* __restrict__ src, bf16* __restrict__ dst,
                      const int* __restrict__ flag, long n) {
    const int f = *flag;
    long i = (long)blockIdx.x * blockDim.x + threadIdx.x;
    const long stride = (long)gridDim.x * blockDim.x;
    if (f) {
        const float* s = (const float*)src;
        for (; i < n; i += stride) dst[i] = __float2bfloat16(s[i]);
    } else {
        const bf16* s = (const bf16*)src;
        for (; i < n; i += stride) dst[i] = s[i];
    }
}

// ---------------------------------------------------------------------------
// Batched 2D transpose + canonicalize: in [Z][R][C] ->
//   out[z*z_out + c*c_stride + r]  (z_out=R*C,c_stride=R gives [Z][C][R])
// ---------------------------------------------------------------------------
__global__ void transpose_k(const void* __restrict__ in, bf16* __restrict__ out,
                            const int* __restrict__ flag, int R, int C,
                            long z_out, long c_stride) {
    __shared__ bf16 t[32][33];
    const int f = *flag;
    const long zi = (long)blockIdx.z * R * C;
    const int x = blockIdx.x * 32 + threadIdx.x;
    const int y0 = blockIdx.y * 32;
    const float* inf = (const float*)in;
    const bf16* inb = (const bf16*)in;
#pragma unroll
    for (int i = 0; i < 4; i++) {
        int r = y0 + threadIdx.y + i * 8;
        long idx = zi + (long)r * C + x;
        t[threadIdx.y + i * 8][threadIdx.x] =
            f ? __float2bfloat16(inf[idx]) : inb[idx];
    }
    __syncthreads();
    const int xr = blockIdx.y * 32 + threadIdx.x;
    const long zo = (long)blockIdx.z * z_out;
#pragma unroll
    for (int i = 0; i < 4; i++) {
        int c = blockIdx.x * 32 + threadIdx.y + i * 8;
        out[zo + (long)c * c_stride + xr] = t[threadIdx.x][threadIdx.y + i * 8];
    }
}

// ---------------------------------------------------------------------------
// Gating layer 3 + softmax: g2 [B,128] @ gw3 [128,8] + gb3 -> softmax -> gates
// ---------------------------------------------------------------------------
__global__ void gate3_softmax_k(const bf16* __restrict__ g2,
                                const bf16* __restrict__ gw3,
                                const bf16* __restrict__ gb3,
                                float* __restrict__ gates) {
    __shared__ float w[128 * 8];
    __shared__ float bsh[8];
    const int tid = threadIdx.x;
    for (int i = tid; i < 1024; i += 256) w[i] = __bfloat162float(gw3[i]);
    if (tid < 8) bsh[tid] = __bfloat162float(gb3[tid]);
    __syncthreads();

    const long row = (long)blockIdx.x * 256 + tid;
    float acc[8];
#pragma unroll
    for (int o = 0; o < 8; o++) acc[o] = bsh[o];

    const bf16x8* rp8 = (const bf16x8*)(g2 + row * 128);
#pragma unroll 4
    for (int c8 = 0; c8 < 16; c8++) {
        bf16x8 v8 = rp8[c8];
#pragma unroll
        for (int jj = 0; jj < 8; jj++) {
            float v = (float)v8[jj];
            int k = c8 * 8 + jj;
#pragma unroll
            for (int o = 0; o < 8; o++) acc[o] += v * w[k * 8 + o];
        }
    }
    float m = acc[0];
#pragma unroll
    for (int o = 1; o < 8; o++) m = fmaxf(m, acc[o]);
    float s = 0.f;
#pragma unroll
    for (int o = 0; o < 8; o++) { acc[o] = __expf(acc[o] - m); s += acc[o]; }
    const float inv = 1.f / s;
#pragma unroll
    for (int o = 0; o < 8; o++) gates[row * 8 + o] = acc[o] * inv;
}

// ---------------------------------------------------------------------------
// Legacy 128x128 GEMM (m97 structure). Used for small gating GEMMs + pathB.
// C[M,N] = A[M,K] * Bt[N,K]^T, BK=32, 4 waves.
// MODE 0: out = bf16(relu(acc + bias[c]))
// MODE 1: out = bf16(relu(acc + bias[c]) * gates[row0+r, e])
// MODE 2: outf32[r,c] += acc + gates[row0+r,e]*eb3[e,c]
// ---------------------------------------------------------------------------
template <int MODE>
__global__ __launch_bounds__(256, 4)
void gemm_bt(const bf16* __restrict__ A, const bf16* __restrict__ Bt,
             const bf16* __restrict__ bias, const float* __restrict__ gates,
             void* __restrict__ Cout, const bf16* __restrict__ eb3,
             const int* __restrict__ oflag,
             int lda, int ldb, int ldo, int K,
             long a_z, long b_z, long bias_z, long out_z,
             int e_gate, int k_per_e, long a_e, long b_e, long row0) {
    __shared__ __attribute__((aligned(16))) bf16 As[128 * 32];
    __shared__ __attribute__((aligned(16))) bf16 Bs[128 * 32];

    const int tid  = threadIdx.x;
    const int lane = tid & 63;
    const int quad = lane >> 4;
    const int l15  = lane & 15;
    const int wid  = tid >> 6;
    const int wr   = (wid >> 1) << 6;
    const int wc   = (wid & 1) << 6;
    const int z    = blockIdx.z;
    const long m0  = (long)blockIdx.y << 7;
    const long n0  = (long)blockIdx.x << 7;

    const bf16* Az = A + (long)z * a_z;
    const bf16* Bz = Bt + (long)z * b_z;

    f32x4 acc[4][4];
#pragma unroll
    for (int i = 0; i < 4; i++)
#pragma unroll
        for (int j = 0; j < 4; j++) acc[i][j] = (f32x4){0.f, 0.f, 0.f, 0.f};

    const int erow = tid >> 2;
    const int ecol = (tid & 3) << 3;

    const int n_e   = k_per_e ? (K / k_per_e) : 1;
    const int inner = (k_per_e ? k_per_e : K) >> 5;

    for (int e = 0; e < n_e; e++) {
        const bf16* Ae = Az + (long)e * a_e;
        const bf16* Be = Bz + (long)e * b_e;
        for (int kti = 0; kti < inner; kti++) {
            const int kk = kti << 5;
#pragma unroll
            for (int i = 0; i < 2; i++) {
                const int r = (i << 6) + erow;
                GLDS(Ae + (m0 + r) * lda + (kk + ecol), As + r * 32 + ecol);
            }
#pragma unroll
            for (int i = 0; i < 2; i++) {
                const int r = (i << 6) + erow;
                GLDS(Be + (n0 + r) * ldb + (kk + ecol), Bs + r * 32 + ecol);
            }
            __syncthreads();
            bf16x8 af[4], bfr[4];
#pragma unroll
            for (int i = 0; i < 4; i++)
                af[i] = *(const bf16x8*)(As + (wr + i * 16 + l15) * 32 + (quad << 3));
#pragma unroll
            for (int j = 0; j < 4; j++)
                bfr[j] = *(const bf16x8*)(Bs + (wc + j * 16 + l15) * 32 + (quad << 3));
#pragma unroll
            for (int i = 0; i < 4; i++)
#pragma unroll
                for (int j = 0; j < 4; j++)
                    acc[i][j] = __builtin_amdgcn_mfma_f32_16x16x32_bf16(
                        af[i], bfr[j], acc[i][j], 0, 0, 0);
            __syncthreads();
        }
    }

    const int eg = (e_gate >= 0) ? e_gate : z;

    if constexpr (MODE == 0 || MODE == 1) {
        bf16* C = (bf16*)Cout + (long)z * out_z;
        const bf16* bb = bias + (long)z * bias_z;
        float gv[4][4];
        if constexpr (MODE == 1) {
#pragma unroll
            for (int i = 0; i < 4; i++)
#pragma unroll
                for (int rg = 0; rg < 4; rg++)
                    gv[i][rg] = gates[(row0 + m0 + wr + i * 16 + quad * 4 + rg) * 8 + eg];
        }
#pragma unroll
        for (int j = 0; j < 4; j++) {
            const int c = (int)n0 + wc + j * 16 + l15;
            const float bv = __bfloat162float(bb[c]);
#pragma unroll
            for (int i = 0; i < 4; i++) {
#pragma unroll
                for (int rg = 0; rg < 4; rg++) {
                    const long r = m0 + wr + i * 16 + quad * 4 + rg;
                    float v = fmaxf(acc[i][j][rg] + bv, 0.f);
                    if constexpr (MODE == 1) v *= gv[i][rg];
                    C[r * ldo + c] = __float2bfloat16(v);
                }
            }
        }
    } else if constexpr (MODE == 2) {
        float* C = (float*)Cout;
#pragma unroll
        for (int i = 0; i < 4; i++) {
#pragma unroll
            for (int rg = 0; rg < 4; rg++) {
                const long r = m0 + wr + i * 16 + quad * 4 + rg;
                const float g = gates[(row0 + r) * 8 + eg];
#pragma unroll
                for (int j = 0; j < 4; j++) {
                    const int c = (int)n0 + wc + j * 16 + l15;
                    const float b3 = __bfloat162float(eb3[eg * O_ + c]);
                    C[r * ldo + c] += acc[i][j][rg] + g * b3;
                }
            }
        }
    }
}

// ---------------------------------------------------------------------------
// 256x256-tile 8-phase GEMM (m201 structure: T1+T2+T3+T4+T5).
// C[M,N] = A[M,K] * Bt[N,K]^T. BK=64, 512 threads = 8 waves (2M x 4N),
// LDS 128 KiB double-buffered.
//
// T2 swizzle (round-2 fix): LDS row = 128 B = 8 granules of 16 B. A
// ds_read_b128 serves 16 rows (l15) x 4 quad-cols; granule index is
// g = col16 ^ swz_g(row). Round-1 used swz_g = 2*(row bit2), which only
// permutes WITHIN the quad-col granule set -> distribution identical to
// linear -> SQ_LDS_BANK_CONFLICT saturated at 2^23, no gain. Correct form
// (G4): byte ^= (row&7)<<4  => g = col16 ^ (row&7), uniform 8 lanes per
// granule = the 1024B/128B-per-clock floor (conflict-free). Same XOR is
// applied to the GLDS per-lane GLOBAL source column (rule 21 both-sides;
// LDS dest stays linear).
//
// Per-iteration schedule (tiles t0=2i in buf0 / t1=2i+1 in buf1):
//  P0 rd(A0,B0|buf0) st Ah1(t1)   P4 rd(A0,B0|buf1) st Ah1(t2)
//  P1 rd(B1|buf0)    st Bh1(t1)   P5 rd(B1|buf1)    st Bh1(t2)
//  P2 rd(A1,B0|buf0) st Ah0(t2)   P6 rd(A1,B0|buf1) st Ah0(t3)
//  P3 rd(B1|buf0)    st Bh0(t2)   P7 rd(B1|buf1)    st Bh0(t3)
//  vmcnt(4) after P3/P7 only (vmcnt(0) drain on the last iteration).
//
// MODE 0: bf16 out = relu(acc + bias[c])                    (z-batched)
// MODE 1: bf16 out = relu(acc + bias[c]) * gates[row0+r,z]  (z-batched)
// MODE 4: fp32 parts[z][r][c] = acc + gates[row0+r,z]*eb3[z,c]  (split-K)
// ---------------------------------------------------------------------------
template <int MODE>
__global__ __launch_bounds__(512, 2)
void gemm256(const bf16* __restrict__ A, const bf16* __restrict__ Bt,
             const bf16* __restrict__ bias, const float* __restrict__ gates,
             void* __restrict__ Cout, const bf16* __restrict__ eb3,
             int lda, int ldb, int ldo, int K,
             long a_z, long b_z, long bias_z, long out_z, long row0) {
    __shared__ __attribute__((aligned(16))) bf16 lds[2][2][256 * 64];

    // T1: bijective XCD swizzle (all launches have nwg%8==0 per z-slice)
    int bx = blockIdx.x, by = blockIdx.y;
    {
        const int gx = gridDim.x;
        const int nwg = gx * gridDim.y;
        if ((nwg & 7) == 0) {
            int lin = bx + gx * by;
            lin = (lin & 7) * (nwg >> 3) + (lin >> 3);
            bx = lin % gx; by = lin / gx;
        }
    }

    const int tid  = threadIdx.x;
    const int lane = tid & 63;
    const int quad = lane >> 4;
    const int l15  = lane & 15;
    const int w    = tid >> 6;
    const int wm   = w >> 2;
    const int wn   = w & 3;
    const int z    = blockIdx.z;
    const long m0  = (long)by << 8;
    const long n0  = (long)bx << 8;

    const bf16* __restrict__ Az = A + z * a_z;
    const bf16* __restrict__ Bz = Bt + z * b_z;

    f32x4 acc[8][4];
#pragma unroll
    for (int i = 0; i < 8; ++i)
#pragma unroll
        for (int j = 0; j < 4; ++j) acc[i][j] = (f32x4){0.f, 0.f, 0.f, 0.f};

    bf16x8 af[4][2], bv[2][2];

    // stage one half-tile (128 rows x 64 cols, 16 KB): 2 GLDS / thread.
    // LDS dest is linear (wave-uniform base + lane*16); swizzle applied by
    // permuting the per-lane GLOBAL source column (rule 21: both-sides).
    auto stage = [&](int buf, int mat, int half, int kt) {
        const bf16* __restrict__ G = mat ? Bz : Az;
        const int ld = mat ? ldb : lda;
        const long p0 = mat ? n0 : m0;
#pragma unroll
        for (int l = 0; l < 2; ++l) {
            const int ci = (w << 1) | l;                       // 0..15, wave-uniform
            const int rb = mat ? ((ci >> 2) << 6) + (half << 5) + ((ci & 3) << 3)
                               : ((ci >> 3) << 7) + (half << 6) + ((ci & 7) << 3);
            const int row = rb + (lane >> 3);
            const int cb  = ((lane & 7) << 4) ^ ((row & 7) << 4);  // T2 inverse-swz src
            GLDS(G + (p0 + row) * ld + kt * 64 + (cb >> 1),
                 &lds[buf][mat][rb * 64]);
        }
    };
    auto ldaf = [&](int buf, int qm) {   // A frags: rows wm*128+qm*64+i*16+l15
#pragma unroll
        for (int i = 0; i < 4; ++i) {
            const int r = (wm << 7) + (qm << 6) + (i << 4) + l15;
            const char* p = (const char*)&lds[buf][0][r * 64];
            const int sw = (r & 7) << 4;
#pragma unroll
            for (int s = 0; s < 2; ++s)
                af[i][s] = *(const bf16x8*)(p + (((s << 6) + (quad << 4)) ^ sw));
        }
    };
    auto ldbf = [&](int buf, int qn) {   // B frags: rows wn*64+qn*32+j*16+l15
#pragma unroll
        for (int j = 0; j < 2; ++j) {
            const int r = (wn << 6) + (qn << 5) + (j << 4) + l15;
            const char* p = (const char*)&lds[buf][1][r * 64];
            const int sw = (r & 7) << 4;
#pragma unroll
            for (int s = 0; s < 2; ++s)
                bv[j][s] = *(const bf16x8*)(p + (((s << 6) + (quad << 4)) ^ sw));
        }
    };
    auto mmac = [&](int qm, int qn) {    // 16 MFMA: one C quadrant x K=64
#pragma unroll
        for (int i = 0; i < 4; ++i)
#pragma unroll
            for (int j = 0; j < 2; ++j)
#pragma unroll
                for (int s = 0; s < 2; ++s)
                    acc[(qm << 2) + i][(qn << 1) + j] =
                        __builtin_amdgcn_mfma_f32_16x16x32_bf16(
                            af[i][s], bv[j][s], acc[(qm << 2) + i][(qn << 1) + j],
                            0, 0, 0);
    };

    const int nt = K >> 6;           // K-tiles (even, >=2 at all call sites)

    // prologue: tile0 full -> buf0; tile1 Ah0,Bh0 -> buf1; guarantee tile0.
    stage(0, 0, 0, 0); stage(0, 0, 1, 0); stage(0, 1, 0, 0); stage(0, 1, 1, 0);
    stage(1, 0, 0, 1); stage(1, 1, 0, 1);
    asm volatile("s_waitcnt vmcnt(4)" ::: "memory");
    BAR();

    const int hi = nt >> 1;
    for (int it = 0; it < hi; ++it) {
        const int t1k = 2 * it + 1, t2k = 2 * it + 2, t3k = 2 * it + 3;
        const bool do2 = t2k < nt, do3 = t3k < nt;
        // P0
        ldaf(0, 0); ldbf(0, 0); stage(1, 0, 1, t1k);
        BAR(); LGKM0();
        __builtin_amdgcn_s_setprio(1); mmac(0, 0); __builtin_amdgcn_s_setprio(0);
        BAR();
        // P1
        ldbf(0, 1); stage(1, 1, 1, t1k);
        BAR(); LGKM0();
        __builtin_amdgcn_s_setprio(1); mmac(0, 1); __builtin_amdgcn_s_setprio(0);
        BAR();
        // P2
        ldaf(0, 1); ldbf(0, 0); if (do2) stage(0, 0, 0, t2k);
        BAR(); LGKM0();
        __builtin_amdgcn_s_setprio(1); mmac(1, 0); __builtin_amdgcn_s_setprio(0);
        BAR();
        // P3
        ldbf(0, 1); if (do2) stage(0, 1, 0, t2k);
        BAR(); LGKM0();
        __builtin_amdgcn_s_setprio(1); mmac(1, 1); __builtin_amdgcn_s_setprio(0);
        if (do2) { asm volatile("s_waitcnt vmcnt(4)" ::: "memory"); }
        else     { asm volatile("s_waitcnt vmcnt(0)" ::: "memory"); }
        BAR();
        // P4
        ldaf(1, 0); ldbf(1, 0); if (do2) stage(0, 0, 1, t2k);
        BAR(); LGKM0();
        __builtin_amdgcn_s_setprio(1); mmac(0, 0); __builtin_amdgcn_s_setprio(0);
        BAR();
        // P5
        ldbf(1, 1); if (do2) stage(0, 1, 1, t2k);
        BAR(); LGKM0();
        __builtin_amdgcn_s_setprio(1); mmac(0, 1); __builtin_amdgcn_s_setprio(0);
        BAR();
        // P6
        ldaf(1, 1); ldbf(1, 0); if (do3) stage(1, 0, 0, t3k);
        BAR(); LGKM0();
        __builtin_amdgcn_s_setprio(1); mmac(1, 0); __builtin_amdgcn_s_setprio(0);
        BAR();
        // P7
        ldbf(1, 1); if (do3) stage(1, 1, 0, t3k);
        BAR(); LGKM0();
        __builtin_amdgcn_s_setprio(1); mmac(1, 1); __builtin_amdgcn_s_setprio(0);
        if (do3) { asm volatile("s_waitcnt vmcnt(4)" ::: "memory"); }
        else     { asm volatile("s_waitcnt vmcnt(0)" ::: "memory"); }
        BAR();
    }

    // ---------------- epilogue (C/D: row=quad*4+reg, col=l15) --------------
    if constexpr (MODE == 0 || MODE == 1) {
        bf16* C = (bf16*)Cout + z * out_z;
        const bf16* bb = bias + z * bias_z;
        float bvv[4];
#pragma unroll
        for (int jg = 0; jg < 4; ++jg)
            bvv[jg] = __bfloat162float(bb[(int)n0 + (wn << 6) + (jg << 4) + l15]);
#pragma unroll
        for (int ig = 0; ig < 8; ++ig) {
#pragma unroll
            for (int rg = 0; rg < 4; ++rg) {
                const long r = m0 + (wm << 7) + (ig << 4) + (quad << 2) + rg;
                float g = 1.f;
                if constexpr (MODE == 1) g = gates[(row0 + r) * 8 + z];
#pragma unroll
                for (int jg = 0; jg < 4; ++jg) {
                    const int c = (int)n0 + (wn << 6) + (jg << 4) + l15;
                    float v = fmaxf(acc[ig][jg][rg] + bvv[jg], 0.f);
                    if constexpr (MODE == 1) v *= g;
                    C[r * ldo + c] = __float2bfloat16(v);
                }
            }
        }
    } else {  // MODE 4: split-K partials, plain stores
        float* C = (float*)Cout + z * out_z;
        float b3v[4];
#pragma unroll
        for (int jg = 0; jg < 4; ++jg)
            b3v[jg] = __bfloat162float(eb3[z * O_ + (int)n0 + (wn << 6) + (jg << 4) + l15]);
#pragma unroll
        for (int ig = 0; ig < 8; ++ig) {
#pragma unroll
            for (int rg = 0; rg < 4; ++rg) {
                const long r = m0 + (wm << 7) + (ig << 4) + (quad << 2) + rg;
                const float g = gates[(row0 + r) * 8 + z];
#pragma unroll
                for (int jg = 0; jg < 4; ++jg) {
                    const int c = (int)n0 + (wn << 6) + (jg << 4) + l15;
                    C[r * ldo + c] = acc[ig][jg][rg] + g * b3v[jg];
                }
            }
        }
    }
}

// ---------------------------------------------------------------------------
__global__ void zero_f32_k(float* __restrict__ p) {
    p[(long)blockIdx.x * 256 + threadIdx.x] = 0.f;
}
__global__ void out_cvt_k(const float* __restrict__ in, void* __restrict__ out,
                          const int* __restrict__ flag) {
    const long i = (long)blockIdx.x * 256 + threadIdx.x;
    if (*flag) ((float*)out)[i] = in[i];
    else       ((bf16*)out)[i] = __float2bfloat16(in[i]);
}
// sum 8 split-K partial buffers [8][BC][O] -> d_out rows [off..off+BC*O)
__global__ void reduce8_k(const float* __restrict__ p, void* __restrict__ out,
                          const int* __restrict__ flag, long off) {
    const long n = (long)BC_ * O_;
    const long i = ((long)blockIdx.x * 256 + threadIdx.x) * 4;
    float4 s = *(const float4*)(p + i);
#pragma unroll
    for (int zz = 1; zz < 8; ++zz) {
        float4 a = *(const float4*)(p + (long)zz * n + i);
        s.x += a.x; s.y += a.y; s.z += a.z; s.w += a.w;
    }
    if (*flag) {
        *(float4*)((float*)out + off + i) = s;
    } else {
        bf16* o = (bf16*)out + off + i;
        o[0] = __float2bfloat16(s.x); o[1] = __float2bfloat16(s.y);
        o[2] = __float2bfloat16(s.z); o[3] = __float2bfloat16(s.w);
    }
}

// ---------------------------------------------------------------------------
extern "C" void kernel_launch(void* const* d_in, const int* in_sizes, int n_in,
                              void* d_out, int out_size, void* d_ws, size_t ws_size,
                              hipStream_t stream) {
    (void)in_sizes; (void)n_in; (void)out_size;
    const void* x   = d_in[0];
    const void* gw1 = d_in[1];
    const void* gb1 = d_in[2];
    const void* gw2 = d_in[3];
    const void* gb2 = d_in[4];
    const void* gw3 = d_in[5];
    const void* gb3 = d_in[6];
    const void* ew1 = d_in[7];
    const void* eb1 = d_in[8];
    const void* ew2 = d_in[9];
    const void* eb2 = d_in[10];
    const void* ew3 = d_in[11];
    const void* eb3 = d_in[12];

    char* ws = (char*)d_ws;
    size_t off = 0;
    auto alloc = [&](size_t n) { char* p = ws + off; off += (n + 255) & ~(size_t)255; return p; };

    int*  flag  = (int*)alloc(256);
    bf16* xc    = (bf16*)alloc((size_t)B_ * D_ * 2);
    bf16* gw1t  = (bf16*)alloc((size_t)256 * 1024 * 2);
    bf16* gw2t  = (bf16*)alloc((size_t)128 * 256 * 2);
    bf16* ew1t  = (bf16*)alloc((size_t)E_ * H_ * D_ * 2);
    bf16* ew2t  = (bf16*)alloc((size_t)E_ * H_ * H_ * 2);
    bf16* ew3t  = (bf16*)alloc((size_t)E_ * O_ * H_ * 2);
    bf16* gb1c  = (bf16*)alloc(256 * 2);
    bf16* gb2c  = (bf16*)alloc(128 * 2);
    bf16* gw3c  = (bf16*)alloc(1024 * 2);
    bf16* gb3c  = (bf16*)alloc(8 * 2);
    bf16* eb1c  = (bf16*)alloc((size_t)E_ * H_ * 2);
    bf16* eb2c  = (bf16*)alloc((size_t)E_ * H_ * 2);
    bf16* eb3c  = (bf16*)alloc((size_t)E_ * O_ * 2);
    bf16* g1    = (bf16*)alloc((size_t)B_ * 256 * 2);
    bf16* g2b   = (bf16*)alloc((size_t)B_ * 128 * 2);
    float* gates = (float*)alloc((size_t)B_ * 8 * 4);

    const size_t small = off;
    // path A: h1c [E][BC][H] + h2 [BC][E*H] (bf16) + parts fp32 [8][BC][O]
    const size_t needA = small + ((size_t)E_ * BC_ * H_ * 2 + 256)
                               + ((size_t)BC_ * E_ * H_ * 2 + 256)
                               + (8ull * BC_ * O_ * 4 + 256) + 4096;
    const bool pathA = ws_size >= needA;

    // 1) detect input dtype (flag=1 -> fp32)
    detect_k<<<1, 256, 0, stream>>>((const unsigned short*)x, flag);

    // 2) canonicalize to bf16
    cvt_k<<<4096, 256, 0, stream>>>(x, xc, flag, (long)B_ * D_);
    cvt_k<<<1, 256, 0, stream>>>(gb1, gb1c, flag, 256);
    cvt_k<<<1, 256, 0, stream>>>(gb2, gb2c, flag, 128);
    cvt_k<<<4, 256, 0, stream>>>(gw3, gw3c, flag, 1024);
    cvt_k<<<1, 256, 0, stream>>>(gb3, gb3c, flag, 8);
    cvt_k<<<16, 256, 0, stream>>>(eb1, eb1c, flag, (long)E_ * H_);
    cvt_k<<<16, 256, 0, stream>>>(eb2, eb2c, flag, (long)E_ * H_);
    cvt_k<<<8, 256, 0, stream>>>(eb3, eb3c, flag, (long)E_ * O_);

    // 3) weight transposes (K-contiguous rows, canonical bf16)
    transpose_k<<<dim3(256 / 32, 1024 / 32, 1), dim3(32, 8), 0, stream>>>(
        gw1, gw1t, flag, 1024, 256, 0L, 1024L);
    transpose_k<<<dim3(128 / 32, 256 / 32, 1), dim3(32, 8), 0, stream>>>(
        gw2, gw2t, flag, 256, 128, 0L, 256L);
    transpose_k<<<dim3(H_ / 32, D_ / 32, E_), dim3(32, 8), 0, stream>>>(
        ew1, ew1t, flag, D_, H_, (long)H_ * D_, (long)D_);
    transpose_k<<<dim3(H_ / 32, H_ / 32, E_), dim3(32, 8), 0, stream>>>(
        ew2, ew2t, flag, H_, H_, (long)H_ * H_, (long)H_);
    if (pathA)  // ew3t as [O][E][H]: single K=4096 L3 GEMM over concat experts
        transpose_k<<<dim3(O_ / 32, H_ / 32, E_), dim3(32, 8), 0, stream>>>(
            ew3, ew3t, flag, H_, O_, (long)H_, (long)E_ * H_);
    else        // legacy [E][O][H]
        transpose_k<<<dim3(O_ / 32, H_ / 32, E_), dim3(32, 8), 0, stream>>>(
            ew3, ew3t, flag, H_, O_, (long)O_ * H_, (long)H_);

    // 4) gating network (small N -> keep 128-tile kernel, full grid)
    gemm_bt<0><<<dim3(2, 128, 1), 256, 0, stream>>>(
        xc, gw1t, gb1c, nullptr, g1, nullptr, nullptr,
        1024, 1024, 256, 1024, 0, 0, 0, 0, 0, 0, 0, 0, 0);
    gemm_bt<0><<<dim3(1, 128, 1), 256, 0, stream>>>(
        g1, gw2t, gb2c, nullptr, g2b, nullptr, nullptr,
        256, 256, 128, 256, 0, 0, 0, 0, 0, 0, 0, 0, 0);
    gate3_softmax_k<<<dim3(B_ / 256), 256, 0, stream>>>(g2b, gw3c, gb3c, gates);

    // 5) experts
    if (pathA) {
        bf16* h1c   = (bf16*)alloc((size_t)E_ * BC_ * H_ * 2);   // [E][BC][H]
        bf16* h2    = (bf16*)alloc((size_t)BC_ * E_ * H_ * 2);   // [BC][E*H]
        float* parts = (float*)alloc(8ull * BC_ * O_ * 4);       // [8][BC][O]
        for (int ch = 0; ch < B_ / BC_; ch++) {
            const long rb = (long)ch * BC_;
            // L1 (z=e batched): h1c[e][r][h] = relu(x_chunk @ ew1[e] + eb1[e])
            gemm256<0><<<dim3(2, BC_ / 256, 8), 512, 0, stream>>>(
                xc + rb * D_, ew1t, eb1c, nullptr, h1c, nullptr,
                D_, D_, H_, D_,
                0, (long)H_ * D_, (long)H_, (long)BC_ * H_, 0);
            // L2 (z=e batched, gates folded): h2[r][e*H+h]
            gemm256<1><<<dim3(2, BC_ / 256, 8), 512, 0, stream>>>(
                h1c, ew2t, eb2c, gates, h2, nullptr,
                H_, H_, E_ * H_, H_,
                (long)BC_ * H_, (long)H_ * H_, (long)H_, (long)H_, rb);
            // L3 split-K over experts (z=8, K=512 each): parts[z] = partial
            gemm256<4><<<dim3(1, BC_ / 256, 8), 512, 0, stream>>>(
                h2, ew3t, nullptr, gates, parts, eb3c,
                E_ * H_, E_ * H_, O_, 512,
                (long)H_, (long)H_, 0, (long)BC_ * O_, rb);
            reduce8_k<<<dim3(BC_ * O_ / 1024), 256, 0, stream>>>(
                parts, d_out, flag, rb * O_);
        }
    } else {
        bf16* h1s = (bf16*)alloc((size_t)B_ * H_ * 2);
        bf16* h2s = (bf16*)alloc((size_t)B_ * H_ * 2);
        float* oacc = (float*)alloc((size_t)B_ * O_ * 4);
        zero_f32_k<<<dim3(B_ * O_ / 256), 256, 0, stream>>>(oacc);
        for (int e = 0; e < E_; e++) {
            gemm_bt<0><<<dim3(4, 128, 1), 256, 0, stream>>>(
                xc, ew1t + (size_t)e * H_ * D_, eb1c + (size_t)e * H_, nullptr, h1s, nullptr, nullptr,
                1024, 1024, 512, 1024, 0, 0, 0, 0, 0, 0, 0, 0, 0);
            gemm_bt<1><<<dim3(4, 128, 1), 256, 0, stream>>>(
                h1s, ew2t + (size_t)e * H_ * H_, eb2c + (size_t)e * H_, gates, h2s, nullptr, nullptr,
                512, 512, 512, 512, 0, 0, 0, 0, e, 0, 0, 0, 0);
            gemm_bt<2><<<dim3(2, 128, 1), 256, 0, stream>>>(
                h2s, ew3t + (size_t)e * O_ * H_, nullptr, gates, oacc, eb3c, nullptr,
                512, 512, 256, 512, 0, 0, 0, 0, e, 0, 0, 0, 0);
        }
        out_cvt_k<<<dim3(B_ * O_ / 256), 256, 0, stream>>>(oacc, d_out, flag);
    }
}